// Round 5
// baseline (242.620 us; speedup 1.0000x reference)
//
#include <hip/hip_runtime.h>

#define NROW 8192
#define INF  512
#define OUTF 256
#define M_ELEM (NROW * OUTF)   // 2,097,152 f32 per output matrix

typedef __bf16 v8bf __attribute__((ext_vector_type(8)));
typedef __bf16 v4bf __attribute__((ext_vector_type(4)));
typedef float  v4f  __attribute__((ext_vector_type(4)));

__device__ __forceinline__ v8bf cvt_bf8(v4f u0, v4f u1) {
  v8bf v;
  v[0]=(__bf16)u0[0]; v[1]=(__bf16)u0[1]; v[2]=(__bf16)u0[2]; v[3]=(__bf16)u0[3];
  v[4]=(__bf16)u1[0]; v[5]=(__bf16)u1[1]; v[6]=(__bf16)u1[2]; v[7]=(__bf16)u1[3];
  return v;
}

// ---------------------------------------------------------------------------
// Kernel A: seq = feat @ W^T, bf16 MFMA, output in B-fragment-packed layout:
//   elem(m,o) -> (((m>>5)*16 + (o>>4))*64 + ((m>>3)&3)*16 + (o&15))*8 + (m&7)
// = 1 KB chunks indexed by (kk=m>>5, cig=o>>4), lane-contiguous inside.
// ---------------------------------------------------------------------------
__global__ __launch_bounds__(256) void seq_fts_kernel(
    const float* __restrict__ feat, const float* __restrict__ W,
    __bf16* __restrict__ Bp) {
  const int tid  = threadIdx.x;
  const int lane = tid & 63, w = tid >> 6;
  const int llo  = lane & 15, lhi = lane >> 4;
  const int row0 = blockIdx.x * 64;
  const int col0 = w * 64;

  v4f acc[4][4] = {};
#pragma unroll 1
  for (int kb = 0; kb < INF / 32; ++kb) {
    const int kofs = kb * 32 + lhi * 8;
    v8bf a[4], b[4];
#pragma unroll
    for (int i = 0; i < 4; ++i) {
      const float* p = feat + (size_t)(row0 + i * 16 + llo) * INF + kofs;
      a[i] = cvt_bf8(*(const v4f*)p, *(const v4f*)(p + 4));
    }
#pragma unroll
    for (int i = 0; i < 4; ++i) {
      const float* p = W + (size_t)(col0 + i * 16 + llo) * INF + kofs;
      b[i] = cvt_bf8(*(const v4f*)p, *(const v4f*)(p + 4));
    }
#pragma unroll
    for (int ri = 0; ri < 4; ++ri)
#pragma unroll
      for (int ci = 0; ci < 4; ++ci)
        acc[ri][ci] = __builtin_amdgcn_mfma_f32_16x16x32_bf16(
            a[ri], b[ci], acc[ri][ci], 0, 0, 0);
  }
#pragma unroll
  for (int ri = 0; ri < 4; ++ri)
#pragma unroll
    for (int ci = 0; ci < 4; ++ci) {
      const int mf = row0 + ri * 16 + lhi * 4;
      const int o  = col0 + ci * 16 + llo;
      size_t e = (((size_t)(mf >> 5) * 16 + (o >> 4)) * 64 +
                  ((mf >> 3) & 3) * 16 + (o & 15)) * 8 + (mf & 7);
      v4bf v;
      v[0] = (__bf16)acc[ri][ci][0]; v[1] = (__bf16)acc[ri][ci][1];
      v[2] = (__bf16)acc[ri][ci][2]; v[3] = (__bf16)acc[ri][ci][3];
      *(v4bf*)(Bp + e) = v;
    }
}

// ---------------------------------------------------------------------------
// Kernel B: out = prelu(adj @ seq + bias).  BM=64, full K per block.
// PRODUCER/CONSUMER wave split (separate vmcnt FIFOs -> no cross-drain):
//  - waves 4..7 (producers): stage A macro-tile 64 rows x 256 k (f32) into
//    2x64KB LDS dbuf via global_load_lds. Each instruction = ONE ROW's 1 KB
//    contiguous chunk (DRAM page-friendly). Source chunk idx pre-swizzled
//    (lane ^ (r&7)) so linear LDS dest is XOR-swizzled.
//  - waves 0..3 (consumers): 16 rows x 256 cols each. B-frags direct from
//    L2-resident packed Bp, 1-micro reg prefetch; MFMA; bias+prelu epilogue.
// ---------------------------------------------------------------------------
__global__ __launch_bounds__(512, 1) void gcn_agg_kernel(
    const float* __restrict__ adjA, const float* __restrict__ adjB,
    const __bf16* __restrict__ Bp, const float* __restrict__ bias,
    const float* __restrict__ prelu_a, float* __restrict__ out) {
  const int tid  = threadIdx.x;
  const int lane = tid & 63, w = tid >> 6;
  const int llo  = lane & 15, lhi = lane >> 4;
  const int row0 = blockIdx.x * 64;
  const int z    = blockIdx.y;
  const float* __restrict__ adj = z ? adjB : adjA;

  __shared__ __align__(16) float Albuf[2][64 * 256];   // 2 x 64 KB

  if (w >= 4) {
    // =============== producer ===============
    const int pw = w - 4;
    auto stage = [&](int buf, int M) {
#pragma unroll
      for (int i = 0; i < 16; ++i) {
        const int r = pw * 16 + i;                       // uniform per instr
        const float* src = adj + (size_t)(row0 + r) * NROW + M * 256 +
                           ((lane ^ (r & 7)) << 2);      // pre-swizzled chunk
        float* dst = &Albuf[buf][r * 256];
        __builtin_amdgcn_global_load_lds(
            (const __attribute__((address_space(1))) void*)src,
            (__attribute__((address_space(3))) void*)dst, 16, 0, 0);
      }
    };
    stage(0, 0);
    asm volatile("s_waitcnt vmcnt(0)" ::: "memory");
    __builtin_amdgcn_s_barrier();
#pragma unroll 1
    for (int M = 0; M < 32; ++M) {
      if (M + 1 < 32) {
        stage((M + 1) & 1, M + 1);
        asm volatile("s_waitcnt vmcnt(0)" ::: "memory");
      }
      asm volatile("" ::: "memory");
      __builtin_amdgcn_s_barrier();
      asm volatile("" ::: "memory");
    }
  } else {
    // =============== consumer ===============
    v4f acc[16] = {};
    v8bf bcur[16], bnxt[16];
    const __bf16* __restrict__ Bpl = Bp + lane * 8;
    auto load_b = [&](int kk, v8bf (&b)[16]) {
#pragma unroll
      for (int ci = 0; ci < 16; ++ci)
        b[ci] = *(const v8bf*)(Bpl + (size_t)(kk * 16 + ci) * 512);
    };
    const int rl = w * 16 + llo;                 // this lane's A row (tile-local)
    const int rs = rl & 7;                       // swizzle key
    const char* abase = (const char*)&Albuf[0][0] + rl * 1024;

    load_b(0, bcur);
    __builtin_amdgcn_s_barrier();
    asm volatile("" ::: "memory");
#pragma unroll 1
    for (int M = 0; M < 32; ++M) {
      const char* ab = abase + (M & 1) * 65536;
#pragma unroll
      for (int km = 0; km < 8; km += 2) {
        {  // micro even: consume bcur, prefetch into bnxt
          const int nk = M * 8 + km + 1;
          load_b(nk, bnxt);
          const int c0 = km * 8 + lhi * 2;
          v4f u0 = *(const v4f*)(ab + (((c0    ) ^ rs) << 4));
          v4f u1 = *(const v4f*)(ab + (((c0 + 1) ^ rs) << 4));
          v8bf af = cvt_bf8(u0, u1);
#pragma unroll
          for (int ci = 0; ci < 16; ++ci)
            acc[ci] = __builtin_amdgcn_mfma_f32_16x16x32_bf16(
                af, bcur[ci], acc[ci], 0, 0, 0);
        }
        {  // micro odd: consume bnxt, prefetch into bcur
          int nk = M * 8 + km + 2; if (nk > 255) nk = 255;
          load_b(nk, bcur);
          const int c0 = (km + 1) * 8 + lhi * 2;
          v4f u0 = *(const v4f*)(ab + (((c0    ) ^ rs) << 4));
          v4f u1 = *(const v4f*)(ab + (((c0 + 1) ^ rs) << 4));
          v8bf af = cvt_bf8(u0, u1);
#pragma unroll
          for (int ci = 0; ci < 16; ++ci)
            acc[ci] = __builtin_amdgcn_mfma_f32_16x16x32_bf16(
                af, bnxt[ci], acc[ci], 0, 0, 0);
        }
      }
      asm volatile("" ::: "memory");
      __builtin_amdgcn_s_barrier();
      asm volatile("" ::: "memory");
    }
    // epilogue: bias + prelu, direct store
    const float slope = prelu_a[0];
    float* __restrict__ outp = out + (size_t)z * M_ELEM;
#pragma unroll
    for (int ci = 0; ci < 16; ++ci) {
      const int o  = ci * 16 + llo;
      const float bs = bias[o];
#pragma unroll
      for (int r = 0; r < 4; ++r) {
        const int m = row0 + w * 16 + lhi * 4 + r;
        float v = acc[ci][r] + bs;
        outp[(size_t)m * OUTF + o] = v >= 0.f ? v : slope * v;
      }
    }
  }
}

extern "C" void kernel_launch(void* const* d_in, const int* in_sizes, int n_in,
                              void* d_out, int out_size, void* d_ws, size_t ws_size,
                              hipStream_t stream) {
  const float* feat = (const float*)d_in[0];
  const float* adj  = (const float*)d_in[1];
  const float* aug  = (const float*)d_in[2];
  const float* W    = (const float*)d_in[3];
  const float* bias = (const float*)d_in[4];
  const float* pa   = (const float*)d_in[5];
  float* out = (float*)d_out;
  __bf16* Bp = (__bf16*)d_ws;                    // 4 MB packed seq_fts

  seq_fts_kernel<<<dim3(NROW / 64), 256, 0, stream>>>(feat, W, Bp);
  gcn_agg_kernel<<<dim3(NROW / 64, 2), 512, 0, stream>>>(
      adj, aug, Bp, bias, pa, out);
}